// Round 1
// baseline (2596.979 us; speedup 1.0000x reference)
//
#include <hip/hip_runtime.h>

typedef __attribute__((ext_vector_type(8))) short short8;
typedef __attribute__((ext_vector_type(4))) float f32x4;

#define DD 128
#define HH 256

__device__ __forceinline__ unsigned short f2bf(float f) {
  unsigned int u = __float_as_uint(f);
  u += 0x7fffu + ((u >> 16) & 1u);
  return (unsigned short)(u >> 16);
}
__device__ __forceinline__ float bf2f(unsigned short s) {
  return __uint_as_float(((unsigned int)s) << 16);
}
__device__ __forceinline__ f32x4 mfma16(short8 a, short8 b, f32x4 c) {
  return __builtin_amdgcn_mfma_f32_16x16x32_bf16(a, b, c, 0, 0, 0);
}

// ---- weight convert: dst[n][k] = bf16(src[(k+kswap)%K][n]), src row stride = Nout
__global__ void wconv(const float* __restrict__ src, unsigned short* __restrict__ dst,
                      int K, int Nout, int kswap) {
  int id = blockIdx.x * 256 + threadIdx.x;
  if (id >= K * Nout) return;
  int n = id / K, k = id - n * K;
  int ks = k + kswap; if (ks >= K) ks -= K;
  dst[n * K + k] = f2bf(src[(size_t)ks * Nout + n]);
}

// ---- edge vectors + fold edge constants into layer-1 biases (1 block, 256 thr)
__global__ void prep_bias(const float* __restrict__ Ew1, const float* __restrict__ Eb1,
                          const float* __restrict__ Ew2, const float* __restrict__ Eb2,
                          const float* __restrict__ Pw1, const float* __restrict__ Pb1,
                          const float* __restrict__ Cw1, const float* __restrict__ Cb1,
                          float* __restrict__ b1P, float* __restrict__ b1C) {
  __shared__ float h1[HH], h0[HH], ein[DD], eout[DD];
  int t = threadIdx.x;
  h1[t] = fmaxf(Ew1[t] + Eb1[t], 0.f);
  h0[t] = fmaxf(Eb1[t], 0.f);
  __syncthreads();
  if (t < DD) {
    float s1 = Eb2[t], s0 = Eb2[t];
    for (int j = 0; j < HH; ++j) { s1 += h1[j] * Ew2[j * DD + t]; s0 += h0[j] * Ew2[j * DD + t]; }
    ein[t]  = fmaxf(s1, 0.f);
    eout[t] = fmaxf(s0, 0.f);
  }
  __syncthreads();
  float bp = Pb1[t], bc = Cb1[t];
  for (int d = 0; d < DD; ++d) {
    bp += eout[d] * Pw1[(size_t)(256 + d) * HH + t];
    bc += ein[d]  * Cw1[(size_t)(256 + d) * HH + t];
  }
  b1P[t] = bp; b1C[t] = bc;
}

// ---- CSR build: degree count, 3-kernel exclusive scan, per-edge position
__global__ void count_k(const int* __restrict__ selfI, const int* __restrict__ parI,
                        int* degP, int* degC, int E) {
  int id = blockIdx.x * 256 + threadIdx.x;
  if (id < E) { atomicAdd(&degP[selfI[id]], 1); atomicAdd(&degC[parI[id]], 1); }
}

__global__ void scan1(const int* __restrict__ src, int* __restrict__ dst,
                      int* __restrict__ part, int n) {
  __shared__ int sh[256];
  int t = threadIdx.x;
  int base = blockIdx.x * 1024 + t * 4;
  int v0 = base + 0 < n ? src[base + 0] : 0;
  int v1 = base + 1 < n ? src[base + 1] : 0;
  int v2 = base + 2 < n ? src[base + 2] : 0;
  int v3 = base + 3 < n ? src[base + 3] : 0;
  int tsum = v0 + v1 + v2 + v3;
  sh[t] = tsum;
  __syncthreads();
  for (int off = 1; off < 256; off <<= 1) {
    int y = (t >= off) ? sh[t - off] : 0;
    __syncthreads();
    if (t >= off) sh[t] += y;
    __syncthreads();
  }
  int ex = sh[t] - tsum;
  if (base + 0 < n) dst[base + 0] = ex;
  if (base + 1 < n) dst[base + 1] = ex + v0;
  if (base + 2 < n) dst[base + 2] = ex + v0 + v1;
  if (base + 3 < n) dst[base + 3] = ex + v0 + v1 + v2;
  if (t == 255) part[blockIdx.x] = sh[255];
}

__global__ void scan2(int* __restrict__ part, int m) {
  __shared__ int sh[256];
  int t = threadIdx.x;
  int carry = 0;
  for (int base = 0; base < m; base += 256) {
    int v = (base + t < m) ? part[base + t] : 0;
    sh[t] = v;
    __syncthreads();
    for (int off = 1; off < 256; off <<= 1) {
      int y = (t >= off) ? sh[t - off] : 0;
      __syncthreads();
      if (t >= off) sh[t] += y;
      __syncthreads();
    }
    if (base + t < m) part[base + t] = carry + sh[t] - v;
    int tot = sh[255];
    __syncthreads();
    carry += tot;
  }
}

__global__ void scan3(int* __restrict__ dst, const int* __restrict__ part, int n) {
  int i = blockIdx.x * 256 + threadIdx.x;
  if (i < n) dst[i] += part[i >> 10];
}

__global__ void copy2(const int* __restrict__ a, int* __restrict__ b,
                      const int* __restrict__ c, int* __restrict__ d, int n) {
  int i = blockIdx.x * 256 + threadIdx.x;
  if (i < n) { b[i] = a[i]; d[i] = c[i]; }
}

__global__ void pos_k(const int* __restrict__ selfI, const int* __restrict__ parI,
                      int* curP, int* curC, int* posP, int* posC, int E) {
  int e = blockIdx.x * 256 + threadIdx.x;
  if (e < E) {
    posP[e] = atomicAdd(&curP[selfI[e]], 1);
    posC[e] = atomicAdd(&curC[parI[e]], 1);
  }
}

// ---- MLP_V: 256 thr / 4 waves, M=32. Finer blocks -> 4 independent blocks/CU
// (same 16 waves/CU as before, but 2x independent phase streams, half barrier scope).
__global__ __launch_bounds__(256, 4) void v_kernel(
    const float* __restrict__ x, const unsigned short* __restrict__ W1t,
    const unsigned short* __restrict__ W2t, const float* __restrict__ b1,
    const float* __restrict__ b2, float* __restrict__ hidden, int n) {
  __shared__ __align__(16) unsigned short A[32 * 136];
  __shared__ __align__(16) unsigned short O1[32 * 264];
  int t = threadIdx.x;
  int w = t >> 6, lane = t & 63, ln = lane & 15, quad = lane >> 4, qo = quad * 8;
  long tile0 = (long)blockIdx.x * 32;
  int rl = t >> 3, part = t & 7;
  int c0 = part * 16;
  long gr = tile0 + rl;
  const float* src = x + (size_t)(gr < n ? gr : 0) * DD + c0;
  unsigned short* arow = A + rl * 136 + c0;
#pragma unroll
  for (int i = 0; i < 4; ++i) {
    float4 v = *(const float4*)(src + i * 4);
    *(ushort4*)(arow + i * 4) = make_ushort4(f2bf(v.x), f2bf(v.y), f2bf(v.z), f2bf(v.w));
  }
  __syncthreads();
  // layer 1 (K=128): wave w -> cols [w*64, w*64+64)
  f32x4 acc[2][4];
#pragma unroll
  for (int m = 0; m < 2; ++m)
#pragma unroll
    for (int nn = 0; nn < 4; ++nn) acc[m][nn] = {0.f, 0.f, 0.f, 0.f};
#pragma unroll
  for (int kt = 0; kt < 4; ++kt) {
    short8 a[2];
#pragma unroll
    for (int m = 0; m < 2; ++m)
      a[m] = *(const short8*)(A + (m * 16 + ln) * 136 + kt * 32 + qo);
#pragma unroll
    for (int nn = 0; nn < 4; ++nn) {
      short8 b = *(const short8*)(W1t + (size_t)(w * 64 + nn * 16 + ln) * 128 + kt * 32 + qo);
#pragma unroll
      for (int m = 0; m < 2; ++m) acc[m][nn] = mfma16(a[m], b, acc[m][nn]);
    }
  }
  // O1 is a distinct buffer with no prior readers -> no barrier needed here
#pragma unroll
  for (int nn = 0; nn < 4; ++nn) {
    int col = w * 64 + nn * 16 + ln;
    float bb = b1[col];
#pragma unroll
    for (int m = 0; m < 2; ++m)
#pragma unroll
      for (int r = 0; r < 4; ++r)
        O1[(m * 16 + quad * 4 + r) * 264 + col] = f2bf(fmaxf(acc[m][nn][r] + bb, 0.f));
  }
  __syncthreads();
  // layer 2 (K=256): wave w -> cols [w*32, w*32+32)
  f32x4 acc2[2][2];
#pragma unroll
  for (int m = 0; m < 2; ++m) { acc2[m][0] = {0.f, 0.f, 0.f, 0.f}; acc2[m][1] = {0.f, 0.f, 0.f, 0.f}; }
#pragma unroll
  for (int kt = 0; kt < 8; ++kt) {
    short8 a2[2];
#pragma unroll
    for (int m = 0; m < 2; ++m)
      a2[m] = *(const short8*)(O1 + (m * 16 + ln) * 264 + kt * 32 + qo);
#pragma unroll
    for (int nn = 0; nn < 2; ++nn) {
      short8 b = *(const short8*)(W2t + (size_t)(w * 32 + nn * 16 + ln) * 256 + kt * 32 + qo);
#pragma unroll
      for (int m = 0; m < 2; ++m) acc2[m][nn] = mfma16(a2[m], b, acc2[m][nn]);
    }
  }
#pragma unroll
  for (int nn = 0; nn < 2; ++nn) {
    int col = w * 32 + nn * 16 + ln;
    float bb = b2[col];
#pragma unroll
    for (int m = 0; m < 2; ++m)
#pragma unroll
      for (int r = 0; r < 4; ++r) {
        long gr2 = tile0 + m * 16 + quad * 4 + r;
        if (gr2 < n) hidden[gr2 * DD + col] = fmaxf(acc2[m][nn][r] + bb, 0.f);
      }
  }
}

// ---- edge kernel: 256 thr / 4 waves, M=32 edges. P+C layer-1 fused over one
// A-tile read. Barriers cut 10 -> 4 per tile; scatter goes register->global
// directly (bf16 stores land as aligned 32B sectors; CSR positions pre-staged
// in LDS) -- no repack round-trip.
__global__ __launch_bounds__(256, 4) void edge_kernel(
    const float* __restrict__ hidden, const int* __restrict__ selfI, const int* __restrict__ parI,
    const int* __restrict__ posP, const int* __restrict__ posC,
    const unsigned short* __restrict__ Pw1t, const unsigned short* __restrict__ Pw2t,
    const unsigned short* __restrict__ Cw1t, const unsigned short* __restrict__ Cw2t,
    const float* __restrict__ b1P, const float* __restrict__ b1C,
    const float* __restrict__ b2P, const float* __restrict__ b2C,
    unsigned short* __restrict__ SpE, unsigned short* __restrict__ ScE, int E) {
  __shared__ __align__(16) unsigned short A[32 * 264];   // [hs|hp] bf16 tile
  __shared__ __align__(16) unsigned short O1[32 * 264];  // layer-1 out
  __shared__ int posS[2][32];                            // CSR dst positions
  int t = threadIdx.x;
  int w = t >> 6, lane = t & 63, ln = lane & 15, quad = lane >> 4, qo = quad * 8;
  long tile0 = (long)blockIdx.x * 32;
  int rl = t >> 3, part = t & 7;
  long ge = tile0 + rl;
  bool vrow = ge < E;
  int si = vrow ? selfI[ge] : 0;
  int pi = vrow ? parI[ge] : 0;
  if (t < 64) {
    int rr = t & 31;
    long gg = tile0 + rr;
    int v = 0;
    if (gg < E) v = (t < 32) ? posP[gg] : posC[gg];
    posS[t >> 5][rr] = v;
  }
  const float* src = (part < 4) ? (hidden + (size_t)si * DD + part * 32)
                                : (hidden + (size_t)pi * DD + (part - 4) * 32);
  unsigned short* dstA = A + rl * 264 + part * 32;
#pragma unroll
  for (int i = 0; i < 8; ++i) {
    float4 v = *(const float4*)(src + i * 4);
    *(ushort4*)(dstA + i * 4) = make_ushort4(f2bf(v.x), f2bf(v.y), f2bf(v.z), f2bf(v.w));
  }
  __syncthreads();

  // fused layer 1 for P and C: one a[2] read feeds 16 MFMAs
  f32x4 accP[2][4], accC[2][4];
#pragma unroll
  for (int m = 0; m < 2; ++m)
#pragma unroll
    for (int nn = 0; nn < 4; ++nn) {
      accP[m][nn] = {0.f, 0.f, 0.f, 0.f};
      accC[m][nn] = {0.f, 0.f, 0.f, 0.f};
    }
#pragma unroll
  for (int kt = 0; kt < 8; ++kt) {
    short8 a[2];
#pragma unroll
    for (int m = 0; m < 2; ++m)
      a[m] = *(const short8*)(A + (m * 16 + ln) * 264 + kt * 32 + qo);
#pragma unroll
    for (int nn = 0; nn < 4; ++nn) {
      short8 bp = *(const short8*)(Pw1t + (size_t)(w * 64 + nn * 16 + ln) * 256 + kt * 32 + qo);
      short8 bc = *(const short8*)(Cw1t + (size_t)(w * 64 + nn * 16 + ln) * 256 + kt * 32 + qo);
#pragma unroll
      for (int m = 0; m < 2; ++m) {
        accP[m][nn] = mfma16(a[m], bp, accP[m][nn]);
        accC[m][nn] = mfma16(a[m], bc, accC[m][nn]);
      }
    }
  }
  // no barrier: O1 has no prior readers this tile (A and O1 are distinct)

#pragma unroll
  for (int mlp = 0; mlp < 2; ++mlp) {
    const unsigned short* W2t = mlp ? Cw2t : Pw2t;
    const float* b1 = mlp ? b1C : b1P;
    const float* b2 = mlp ? b2C : b2P;
    unsigned short* Sout = mlp ? ScE : SpE;
    if (mlp) __syncthreads();  // prior mlp's layer-2 O1 reads done
    // write O1 = relu(acc + b1)
#pragma unroll
    for (int nn = 0; nn < 4; ++nn) {
      int col = w * 64 + nn * 16 + ln;
      float bb = b1[col];
#pragma unroll
      for (int m = 0; m < 2; ++m)
#pragma unroll
        for (int r = 0; r < 4; ++r) {
          float v = mlp ? accC[m][nn][r] : accP[m][nn][r];
          O1[(m * 16 + quad * 4 + r) * 264 + col] = f2bf(fmaxf(v + bb, 0.f));
        }
    }
    __syncthreads();
    // layer 2: wave w -> cols [w*32, w*32+32)
    f32x4 acc2[2][2];
#pragma unroll
    for (int m = 0; m < 2; ++m) { acc2[m][0] = {0.f, 0.f, 0.f, 0.f}; acc2[m][1] = {0.f, 0.f, 0.f, 0.f}; }
#pragma unroll
    for (int kt = 0; kt < 8; ++kt) {
      short8 a2[2];
#pragma unroll
      for (int m = 0; m < 2; ++m)
        a2[m] = *(const short8*)(O1 + (m * 16 + ln) * 264 + kt * 32 + qo);
#pragma unroll
      for (int nn = 0; nn < 2; ++nn) {
        short8 b = *(const short8*)(W2t + (size_t)(w * 32 + nn * 16 + ln) * 256 + kt * 32 + qo);
#pragma unroll
        for (int m = 0; m < 2; ++m) acc2[m][nn] = mfma16(a2[m], b, acc2[m][nn]);
      }
    }
    // direct register->global scatter: per store inst, 16 lanes x 2B = aligned
    // 32B sector per (quad,row); positions broadcast from LDS.
#pragma unroll
    for (int nn = 0; nn < 2; ++nn) {
      int col = w * 32 + nn * 16 + ln;
      float bb = b2[col];
#pragma unroll
      for (int m = 0; m < 2; ++m)
#pragma unroll
        for (int r = 0; r < 4; ++r) {
          int row = m * 16 + quad * 4 + r;
          if (tile0 + row < E) {
            int dpos = posS[mlp][row];
            Sout[(size_t)dpos * DD + col] = f2bf(fmaxf(acc2[m][nn][r] + bb, 0.f));
          }
        }
    }
  }
}

// ---- node kernel: 256 thr / 4 waves, M=32. CSR gather-mean, build [h|S_p|S_c],
// MLP_A (K=384), residual add. O1 overlaid on A (LDS 25KB -> 4 blocks/CU).
__global__ __launch_bounds__(256, 4) void node_kernel(
    float* __restrict__ hidden,
    const unsigned short* __restrict__ SpE, const unsigned short* __restrict__ ScE,
    const int* __restrict__ offP, const int* __restrict__ degP,
    const int* __restrict__ offC, const int* __restrict__ degC,
    const float* __restrict__ rootM, const float* __restrict__ leafM,
    const float* __restrict__ startT, const float* __restrict__ endT,
    const unsigned short* __restrict__ W1t, const unsigned short* __restrict__ W2t,
    const float* __restrict__ b1, const float* __restrict__ b2, int n) {
  __shared__ __align__(16) unsigned short A[32 * 392];
  int t = threadIdx.x;
  int w = t >> 6, lane = t & 63, ln = lane & 15, quad = lane >> 4, qo = quad * 8;
  long tile0 = (long)blockIdx.x * 32;
  int rl = t >> 3, part = t & 7;
  int c0 = part * 16;
  long gr = tile0 + rl;
  long g = (gr < n) ? gr : 0;
  unsigned short* arow = A + rl * 392;
  {  // h cols
    const float* hrow = hidden + (size_t)g * DD + c0;
#pragma unroll
    for (int i = 0; i < 4; ++i) {
      float4 h = *(const float4*)(hrow + i * 4);
      *(ushort4*)(arow + c0 + i * 4) = make_ushort4(f2bf(h.x), f2bf(h.y), f2bf(h.z), f2bf(h.w));
    }
  }
  {  // S_p mean: contiguous CSR rows
    int off = offP[g], dg = degP[g];
    float s[16];
#pragma unroll
    for (int i = 0; i < 16; ++i) s[i] = 0.f;
    for (int j = 0; j < dg; ++j) {
      const unsigned short* rr = SpE + (size_t)(off + j) * DD + c0;
#pragma unroll
      for (int i = 0; i < 4; ++i) {
        ushort4 u = *(const ushort4*)(rr + i * 4);
        s[i * 4 + 0] += bf2f(u.x); s[i * 4 + 1] += bf2f(u.y);
        s[i * 4 + 2] += bf2f(u.z); s[i * 4 + 3] += bf2f(u.w);
      }
    }
    float ip = 1.f / fmaxf((float)dg, 1.f);
    float rm = rootM[g];
#pragma unroll
    for (int i = 0; i < 4; ++i) {
      float4 st = *(const float4*)(startT + c0 + i * 4);
      *(ushort4*)(arow + 128 + c0 + i * 4) = make_ushort4(
          f2bf(s[i * 4 + 0] * ip + rm * st.x), f2bf(s[i * 4 + 1] * ip + rm * st.y),
          f2bf(s[i * 4 + 2] * ip + rm * st.z), f2bf(s[i * 4 + 3] * ip + rm * st.w));
    }
  }
  {  // S_c mean
    int off = offC[g], dg = degC[g];
    float s[16];
#pragma unroll
    for (int i = 0; i < 16; ++i) s[i] = 0.f;
    for (int j = 0; j < dg; ++j) {
      const unsigned short* rr = ScE + (size_t)(off + j) * DD + c0;
#pragma unroll
      for (int i = 0; i < 4; ++i) {
        ushort4 u = *(const ushort4*)(rr + i * 4);
        s[i * 4 + 0] += bf2f(u.x); s[i * 4 + 1] += bf2f(u.y);
        s[i * 4 + 2] += bf2f(u.z); s[i * 4 + 3] += bf2f(u.w);
      }
    }
    float ic = 1.f / fmaxf((float)dg, 1.f);
    float lm = leafM[g];
#pragma unroll
    for (int i = 0; i < 4; ++i) {
      float4 et = *(const float4*)(endT + c0 + i * 4);
      *(ushort4*)(arow + 256 + c0 + i * 4) = make_ushort4(
          f2bf(s[i * 4 + 0] * ic + lm * et.x), f2bf(s[i * 4 + 1] * ic + lm * et.y),
          f2bf(s[i * 4 + 2] * ic + lm * et.z), f2bf(s[i * 4 + 3] * ic + lm * et.w));
    }
  }
  __syncthreads();
  // layer 1 (K=384): wave w -> cols [w*64, w*64+64)
  f32x4 acc[2][4];
#pragma unroll
  for (int m = 0; m < 2; ++m)
#pragma unroll
    for (int nn = 0; nn < 4; ++nn) acc[m][nn] = {0.f, 0.f, 0.f, 0.f};
#pragma unroll
  for (int kt = 0; kt < 12; ++kt) {
    short8 a[2];
#pragma unroll
    for (int m = 0; m < 2; ++m)
      a[m] = *(const short8*)(A + (m * 16 + ln) * 392 + kt * 32 + qo);
#pragma unroll
    for (int nn = 0; nn < 4; ++nn) {
      short8 b = *(const short8*)(W1t + (size_t)(w * 64 + nn * 16 + ln) * 384 + kt * 32 + qo);
#pragma unroll
      for (int m = 0; m < 2; ++m) acc[m][nn] = mfma16(a[m], b, acc[m][nn]);
    }
  }
  __syncthreads();  // all A reads done -> overlay O1 into A storage
#pragma unroll
  for (int nn = 0; nn < 4; ++nn) {
    int col = w * 64 + nn * 16 + ln;
    float bb = b1[col];
#pragma unroll
    for (int m = 0; m < 2; ++m)
#pragma unroll
      for (int r = 0; r < 4; ++r)
        A[(m * 16 + quad * 4 + r) * 392 + col] = f2bf(fmaxf(acc[m][nn][r] + bb, 0.f));
  }
  __syncthreads();
  // layer 2 (K=256): wave w -> cols [w*32, w*32+32)
  f32x4 acc2[2][2];
#pragma unroll
  for (int m = 0; m < 2; ++m) { acc2[m][0] = {0.f, 0.f, 0.f, 0.f}; acc2[m][1] = {0.f, 0.f, 0.f, 0.f}; }
#pragma unroll
  for (int kt = 0; kt < 8; ++kt) {
    short8 a2[2];
#pragma unroll
    for (int m = 0; m < 2; ++m)
      a2[m] = *(const short8*)(A + (m * 16 + ln) * 392 + kt * 32 + qo);
#pragma unroll
    for (int nn = 0; nn < 2; ++nn) {
      short8 b = *(const short8*)(W2t + (size_t)(w * 32 + nn * 16 + ln) * 256 + kt * 32 + qo);
#pragma unroll
      for (int m = 0; m < 2; ++m) acc2[m][nn] = mfma16(a2[m], b, acc2[m][nn]);
    }
  }
  __syncthreads();  // O1 reads done -> overlay fp32 repack (keeps residual in fp32)
#pragma unroll
  for (int nn = 0; nn < 2; ++nn) {
    int col = w * 32 + nn * 16 + ln;
    float bb = b2[col];
#pragma unroll
    for (int m = 0; m < 2; ++m)
#pragma unroll
      for (int r = 0; r < 4; ++r)
        ((float*)(A + (size_t)(m * 16 + quad * 4 + r) * 392))[col] =
            fmaxf(acc2[m][nn][r] + bb, 0.f);
  }
  __syncthreads();
  if (gr < n) {
    const float* F = (const float*)(A + (size_t)rl * 392);
    float* hrow = hidden + (size_t)gr * DD + c0;
#pragma unroll
    for (int i = 0; i < 4; ++i) {
      float4 v = *(const float4*)(F + c0 + i * 4);
      float4 h = *(const float4*)(hrow + i * 4);
      h.x += v.x; h.y += v.y; h.z += v.z; h.w += v.w;
      *(float4*)(hrow + i * 4) = h;
    }
  }
}

extern "C" void kernel_launch(void* const* d_in, const int* in_sizes, int n_in,
                              void* d_out, int out_size, void* d_ws, size_t ws_size,
                              hipStream_t stream) {
  const float* batch  = (const float*)d_in[0];
  const int*   selfI  = (const int*)d_in[1];
  const int*   parI   = (const int*)d_in[2];
  const float* rootM  = (const float*)d_in[3];
  const float* leafM  = (const float*)d_in[4];
  const float* startT = (const float*)d_in[5];
  const float* endT   = (const float*)d_in[6];
  const float* Vw1 = (const float*)d_in[7],  *Vb1 = (const float*)d_in[8];
  const float* Vw2 = (const float*)d_in[9],  *Vb2 = (const float*)d_in[10];
  const float* Ew1 = (const float*)d_in[11], *Eb1 = (const float*)d_in[12];
  const float* Ew2 = (const float*)d_in[13], *Eb2 = (const float*)d_in[14];
  const float* Pw1 = (const float*)d_in[15], *Pb1 = (const float*)d_in[16];
  const float* Pw2 = (const float*)d_in[17], *Pb2 = (const float*)d_in[18];
  const float* Cw1 = (const float*)d_in[19], *Cb1 = (const float*)d_in[20];
  const float* Cw2 = (const float*)d_in[21], *Cb2 = (const float*)d_in[22];
  const float* Aw1 = (const float*)d_in[23], *Ab1 = (const float*)d_in[24];
  const float* Aw2 = (const float*)d_in[25], *Ab2 = (const float*)d_in[26];

  const int N = in_sizes[3];
  const int E = in_sizes[1];
  float* out = (float*)d_out;

  char* p = (char*)d_ws;
  auto nxt = [&](size_t sz) { char* r = p; p += (sz + 255) & ~(size_t)255; return r; };
  unsigned short* SpE = (unsigned short*)nxt((size_t)E * DD * 2);
  unsigned short* ScE = (unsigned short*)nxt((size_t)E * DD * 2);
  int* degP = (int*)nxt((size_t)N * 4);
  int* degC = (int*)nxt((size_t)N * 4);
  int* offP = (int*)nxt((size_t)N * 4);
  int* offC = (int*)nxt((size_t)N * 4);
  int* curP = (int*)nxt((size_t)N * 4);
  int* curC = (int*)nxt((size_t)N * 4);
  int* posP = (int*)nxt((size_t)E * 4);
  int* posC = (int*)nxt((size_t)E * 4);
  int* partA = (int*)nxt(4096);
  int* partB = (int*)nxt(4096);
  unsigned short* Vw1t = (unsigned short*)nxt((size_t)128 * 256 * 2);
  unsigned short* Vw2t = (unsigned short*)nxt((size_t)256 * 128 * 2);
  unsigned short* Pw1t = (unsigned short*)nxt((size_t)256 * 256 * 2);
  unsigned short* Pw2t = (unsigned short*)nxt((size_t)256 * 128 * 2);
  unsigned short* Cw1t = (unsigned short*)nxt((size_t)256 * 256 * 2);
  unsigned short* Cw2t = (unsigned short*)nxt((size_t)256 * 128 * 2);
  unsigned short* Aw1t = (unsigned short*)nxt((size_t)384 * 256 * 2);
  unsigned short* Aw2t = (unsigned short*)nxt((size_t)256 * 128 * 2);
  float* b1P = (float*)nxt(256 * 4);
  float* b1C = (float*)nxt(256 * 4);
  // total ws usage ~137 MB (proven-safe envelope)

  hipMemsetAsync(degP, 0, (size_t)N * 4, stream);
  hipMemsetAsync(degC, 0, (size_t)N * 4, stream);

  auto blk = [](int total) { return dim3((total + 255) / 256); };
  wconv<<<blk(128 * 256), 256, 0, stream>>>(Vw1, Vw1t, 128, 256, 0);
  wconv<<<blk(256 * 128), 256, 0, stream>>>(Vw2, Vw2t, 256, 128, 0);
  wconv<<<blk(256 * 256), 256, 0, stream>>>(Pw1, Pw1t, 256, 256, 128);  // half-swap
  wconv<<<blk(256 * 128), 256, 0, stream>>>(Pw2, Pw2t, 256, 128, 0);
  wconv<<<blk(256 * 256), 256, 0, stream>>>(Cw1, Cw1t, 256, 256, 0);
  wconv<<<blk(256 * 128), 256, 0, stream>>>(Cw2, Cw2t, 256, 128, 0);
  wconv<<<blk(384 * 256), 256, 0, stream>>>(Aw1, Aw1t, 384, 256, 0);
  wconv<<<blk(256 * 128), 256, 0, stream>>>(Aw2, Aw2t, 256, 128, 0);

  prep_bias<<<1, 256, 0, stream>>>(Ew1, Eb1, Ew2, Eb2, Pw1, Pb1, Cw1, Cb1, b1P, b1C);
  count_k<<<blk(E), 256, 0, stream>>>(selfI, parI, degP, degC, E);

  int NB = (N + 1023) / 1024;
  scan1<<<NB, 256, 0, stream>>>(degP, offP, partA, N);
  scan1<<<NB, 256, 0, stream>>>(degC, offC, partB, N);
  scan2<<<1, 256, 0, stream>>>(partA, NB);
  scan2<<<1, 256, 0, stream>>>(partB, NB);
  scan3<<<blk(N), 256, 0, stream>>>(offP, partA, N);
  scan3<<<blk(N), 256, 0, stream>>>(offC, partB, N);
  copy2<<<blk(N), 256, 0, stream>>>(offP, curP, offC, curC, N);
  pos_k<<<blk(E), 256, 0, stream>>>(selfI, parI, curP, curC, posP, posC, E);

  dim3 gN((N + 31) / 32), gE((E + 31) / 32);
  v_kernel<<<gN, 256, 0, stream>>>(batch, Vw1t, Vw2t, Vb1, Vb2, out, N);

  for (int hop = 0; hop < 3; ++hop) {
    edge_kernel<<<gE, 256, 0, stream>>>(out, selfI, parI, posP, posC,
                                        Pw1t, Pw2t, Cw1t, Cw2t, b1P, b1C, Pb2, Cb2,
                                        SpE, ScE, E);
    node_kernel<<<gN, 256, 0, stream>>>(out, SpE, ScE, offP, degP, offC, degC,
                                        rootM, leafM, startT, endT,
                                        Aw1t, Aw2t, Ab1, Ab2, N);
  }
}

// Round 3
// 1883.135 us; speedup vs baseline: 1.3791x; 1.3791x over previous
//
#include <hip/hip_runtime.h>

typedef __attribute__((ext_vector_type(8))) short short8;
typedef __attribute__((ext_vector_type(4))) float f32x4;

#define DD 128
#define HH 256

__device__ __forceinline__ unsigned short f2bf(float f) {
  unsigned int u = __float_as_uint(f);
  u += 0x7fffu + ((u >> 16) & 1u);
  return (unsigned short)(u >> 16);
}
__device__ __forceinline__ float bf2f(unsigned short s) {
  return __uint_as_float(((unsigned int)s) << 16);
}
__device__ __forceinline__ f32x4 mfma16(short8 a, short8 b, f32x4 c) {
  return __builtin_amdgcn_mfma_f32_16x16x32_bf16(a, b, c, 0, 0, 0);
}

// ---- weight convert: dst[n][k] = bf16(src[(k+kswap)%K][n]), src row stride = Nout
__global__ void wconv(const float* __restrict__ src, unsigned short* __restrict__ dst,
                      int K, int Nout, int kswap) {
  int id = blockIdx.x * 256 + threadIdx.x;
  if (id >= K * Nout) return;
  int n = id / K, k = id - n * K;
  int ks = k + kswap; if (ks >= K) ks -= K;
  dst[n * K + k] = f2bf(src[(size_t)ks * Nout + n]);
}

// ---- edge vectors + fold edge constants into layer-1 biases (1 block, 256 thr)
__global__ void prep_bias(const float* __restrict__ Ew1, const float* __restrict__ Eb1,
                          const float* __restrict__ Ew2, const float* __restrict__ Eb2,
                          const float* __restrict__ Pw1, const float* __restrict__ Pb1,
                          const float* __restrict__ Cw1, const float* __restrict__ Cb1,
                          float* __restrict__ b1P, float* __restrict__ b1C) {
  __shared__ float h1[HH], h0[HH], ein[DD], eout[DD];
  int t = threadIdx.x;
  h1[t] = fmaxf(Ew1[t] + Eb1[t], 0.f);
  h0[t] = fmaxf(Eb1[t], 0.f);
  __syncthreads();
  if (t < DD) {
    float s1 = Eb2[t], s0 = Eb2[t];
    for (int j = 0; j < HH; ++j) { s1 += h1[j] * Ew2[j * DD + t]; s0 += h0[j] * Ew2[j * DD + t]; }
    ein[t]  = fmaxf(s1, 0.f);
    eout[t] = fmaxf(s0, 0.f);
  }
  __syncthreads();
  float bp = Pb1[t], bc = Cb1[t];
  for (int d = 0; d < DD; ++d) {
    bp += eout[d] * Pw1[(size_t)(256 + d) * HH + t];
    bc += ein[d]  * Cw1[(size_t)(256 + d) * HH + t];
  }
  b1P[t] = bp; b1C[t] = bc;
}

// ---- CSR build: degree count, 3-kernel exclusive scan, per-edge position
__global__ void count_k(const int* __restrict__ selfI, const int* __restrict__ parI,
                        int* degP, int* degC, int E) {
  int id = blockIdx.x * 256 + threadIdx.x;
  if (id < E) { atomicAdd(&degP[selfI[id]], 1); atomicAdd(&degC[parI[id]], 1); }
}

__global__ void scan1(const int* __restrict__ src, int* __restrict__ dst,
                      int* __restrict__ part, int n) {
  __shared__ int sh[256];
  int t = threadIdx.x;
  int base = blockIdx.x * 1024 + t * 4;
  int v0 = base + 0 < n ? src[base + 0] : 0;
  int v1 = base + 1 < n ? src[base + 1] : 0;
  int v2 = base + 2 < n ? src[base + 2] : 0;
  int v3 = base + 3 < n ? src[base + 3] : 0;
  int tsum = v0 + v1 + v2 + v3;
  sh[t] = tsum;
  __syncthreads();
  for (int off = 1; off < 256; off <<= 1) {
    int y = (t >= off) ? sh[t - off] : 0;
    __syncthreads();
    if (t >= off) sh[t] += y;
    __syncthreads();
  }
  int ex = sh[t] - tsum;
  if (base + 0 < n) dst[base + 0] = ex;
  if (base + 1 < n) dst[base + 1] = ex + v0;
  if (base + 2 < n) dst[base + 2] = ex + v0 + v1;
  if (base + 3 < n) dst[base + 3] = ex + v0 + v1 + v2;
  if (t == 255) part[blockIdx.x] = sh[255];
}

__global__ void scan2(int* __restrict__ part, int m) {
  __shared__ int sh[256];
  int t = threadIdx.x;
  int carry = 0;
  for (int base = 0; base < m; base += 256) {
    int v = (base + t < m) ? part[base + t] : 0;
    sh[t] = v;
    __syncthreads();
    for (int off = 1; off < 256; off <<= 1) {
      int y = (t >= off) ? sh[t - off] : 0;
      __syncthreads();
      if (t >= off) sh[t] += y;
      __syncthreads();
    }
    if (base + t < m) part[base + t] = carry + sh[t] - v;
    int tot = sh[255];
    __syncthreads();
    carry += tot;
  }
}

__global__ void scan3(int* __restrict__ dst, const int* __restrict__ part, int n) {
  int i = blockIdx.x * 256 + threadIdx.x;
  if (i < n) dst[i] += part[i >> 10];
}

__global__ void copy2(const int* __restrict__ a, int* __restrict__ b,
                      const int* __restrict__ c, int* __restrict__ d, int n) {
  int i = blockIdx.x * 256 + threadIdx.x;
  if (i < n) { b[i] = a[i]; d[i] = c[i]; }
}

__global__ void pos_k(const int* __restrict__ selfI, const int* __restrict__ parI,
                      int* curP, int* curC, int* posP, int* posC, int E) {
  int e = blockIdx.x * 256 + threadIdx.x;
  if (e < E) {
    posP[e] = atomicAdd(&curP[selfI[e]], 1);
    posC[e] = atomicAdd(&curC[parI[e]], 1);
  }
}

// ---- cooperative MLP_V: 512 thr / 8 waves, waves split N-dim.
// K=128 -> 256 -> 128. Also emits bf16 mirror of hidden (for edge gathers).
__global__ __launch_bounds__(512, 4) void v_kernel(
    const float* __restrict__ x, const unsigned short* __restrict__ W1t,
    const unsigned short* __restrict__ W2t, const float* __restrict__ b1,
    const float* __restrict__ b2, float* __restrict__ hidden,
    unsigned short* __restrict__ hbf, int n) {
  __shared__ __align__(16) unsigned short A[64 * 136];
  __shared__ __align__(16) unsigned short O1[64 * 264];
  int t = threadIdx.x;
  int w = t >> 6, lane = t & 63, ln = lane & 15, quad = lane >> 4, qo = quad * 8;
  long tile0 = (long)blockIdx.x * 64;
  int rl = t >> 3, part = t & 7;
  int c0 = part * 16;
  long gr = tile0 + rl;
  const float* src = x + (size_t)(gr < n ? gr : 0) * DD + c0;
  unsigned short* arow = A + rl * 136 + c0;
#pragma unroll
  for (int i = 0; i < 4; ++i) {
    float4 v = *(const float4*)(src + i * 4);
    *(ushort4*)(arow + i * 4) = make_ushort4(f2bf(v.x), f2bf(v.y), f2bf(v.z), f2bf(v.w));
  }
  __syncthreads();
  // layer 1 (K=128): wave w -> cols [w*32, w*32+32)
  f32x4 acc[4][2];
#pragma unroll
  for (int m = 0; m < 4; ++m) {
    acc[m][0] = {0.f, 0.f, 0.f, 0.f}; acc[m][1] = {0.f, 0.f, 0.f, 0.f};
  }
#pragma unroll
  for (int kt = 0; kt < 4; ++kt) {
    short8 a[4];
#pragma unroll
    for (int m = 0; m < 4; ++m)
      a[m] = *(const short8*)(A + (m * 16 + ln) * 136 + kt * 32 + qo);
#pragma unroll
    for (int nn = 0; nn < 2; ++nn) {
      short8 b = *(const short8*)(W1t + (size_t)(w * 32 + nn * 16 + ln) * 128 + kt * 32 + qo);
#pragma unroll
      for (int m = 0; m < 4; ++m) acc[m][nn] = mfma16(a[m], b, acc[m][nn]);
    }
  }
#pragma unroll
  for (int nn = 0; nn < 2; ++nn) {
    int col = w * 32 + nn * 16 + ln;
    float bb = b1[col];
#pragma unroll
    for (int m = 0; m < 4; ++m)
#pragma unroll
      for (int r = 0; r < 4; ++r)
        O1[(m * 16 + quad * 4 + r) * 264 + col] = f2bf(fmaxf(acc[m][nn][r] + bb, 0.f));
  }
  __syncthreads();
  // layer 2 (K=256): wave w -> cols [w*16, w*16+16)
  f32x4 acc2[4];
#pragma unroll
  for (int m = 0; m < 4; ++m) acc2[m] = {0.f, 0.f, 0.f, 0.f};
#pragma unroll
  for (int kt = 0; kt < 8; ++kt) {
    short8 b = *(const short8*)(W2t + (size_t)(w * 16 + ln) * 256 + kt * 32 + qo);
#pragma unroll
    for (int m = 0; m < 4; ++m) {
      short8 a = *(const short8*)(O1 + (m * 16 + ln) * 264 + kt * 32 + qo);
      acc2[m] = mfma16(a, b, acc2[m]);
    }
  }
  {
    int col = w * 16 + ln;
    float bb = b2[col];
#pragma unroll
    for (int m = 0; m < 4; ++m)
#pragma unroll
      for (int r = 0; r < 4; ++r) {
        long gr2 = tile0 + m * 16 + quad * 4 + r;
        if (gr2 < n) {
          float v = fmaxf(acc2[m][r] + bb, 0.f);
          hidden[gr2 * DD + col] = v;
          if (hbf) hbf[gr2 * DD + col] = f2bf(v);
        }
      }
  }
}

// ---- cooperative edge kernel: 512 thr / 8 waves, M=64 edges, waves split N-dim.
// P+C layer-1 FUSED over one A-tile read. Gather reads bf16 mirror when
// available (half the bytes, no f2bf VALU in the gather).
__global__ __launch_bounds__(512, 4) void edge_kernel(
    const float* __restrict__ hidden, const unsigned short* __restrict__ hbf,
    const int* __restrict__ selfI, const int* __restrict__ parI,
    const int* __restrict__ posP, const int* __restrict__ posC,
    const unsigned short* __restrict__ Pw1t, const unsigned short* __restrict__ Pw2t,
    const unsigned short* __restrict__ Cw1t, const unsigned short* __restrict__ Cw2t,
    const float* __restrict__ b1P, const float* __restrict__ b1C,
    const float* __restrict__ b2P, const float* __restrict__ b2C,
    unsigned short* __restrict__ SpE, unsigned short* __restrict__ ScE, int E) {
  __shared__ __align__(16) unsigned short A[64 * 264];   // [hs|hp] bf16 tile
  __shared__ __align__(16) unsigned short O1[64 * 264];  // layer-1 out / repack buf
  int t = threadIdx.x;
  int w = t >> 6, lane = t & 63, ln = lane & 15, quad = lane >> 4, qo = quad * 8;
  long tile0 = (long)blockIdx.x * 64;
  int rl = t >> 3, part = t & 7;
  long ge = tile0 + rl;
  bool vrow = ge < E;
  int si = vrow ? selfI[ge] : 0;
  int pi = vrow ? parI[ge] : 0;
  unsigned short* dstA = A + rl * 264 + part * 32;
  if (hbf) {
    const unsigned short* srcb = (part < 4) ? (hbf + (size_t)si * DD + part * 32)
                                            : (hbf + (size_t)pi * DD + (part - 4) * 32);
#pragma unroll
    for (int i = 0; i < 4; ++i)
      *(short8*)(dstA + i * 8) = *(const short8*)(srcb + i * 8);
  } else {
    const float* src = (part < 4) ? (hidden + (size_t)si * DD + part * 32)
                                  : (hidden + (size_t)pi * DD + (part - 4) * 32);
#pragma unroll
    for (int i = 0; i < 8; ++i) {
      float4 v = *(const float4*)(src + i * 4);
      *(ushort4*)(dstA + i * 4) = make_ushort4(f2bf(v.x), f2bf(v.y), f2bf(v.z), f2bf(v.w));
    }
  }
  __syncthreads();

  // fused layer 1 for P and C: one a[4] read feeds 16 MFMAs
  f32x4 accP[4][2], accC[4][2];
#pragma unroll
  for (int m = 0; m < 4; ++m) {
    accP[m][0] = {0.f, 0.f, 0.f, 0.f}; accP[m][1] = {0.f, 0.f, 0.f, 0.f};
    accC[m][0] = {0.f, 0.f, 0.f, 0.f}; accC[m][1] = {0.f, 0.f, 0.f, 0.f};
  }
#pragma unroll
  for (int kt = 0; kt < 8; ++kt) {
    short8 a[4];
#pragma unroll
    for (int m = 0; m < 4; ++m)
      a[m] = *(const short8*)(A + (m * 16 + ln) * 264 + kt * 32 + qo);
#pragma unroll
    for (int nn = 0; nn < 2; ++nn) {
      short8 bp = *(const short8*)(Pw1t + (size_t)(w * 32 + nn * 16 + ln) * 256 + kt * 32 + qo);
      short8 bc = *(const short8*)(Cw1t + (size_t)(w * 32 + nn * 16 + ln) * 256 + kt * 32 + qo);
#pragma unroll
      for (int m = 0; m < 4; ++m) {
        accP[m][nn] = mfma16(a[m], bp, accP[m][nn]);
        accC[m][nn] = mfma16(a[m], bc, accC[m][nn]);
      }
    }
  }
  // no barrier: A and O1 are distinct buffers; O1 has no readers yet

#pragma unroll
  for (int mlp = 0; mlp < 2; ++mlp) {
    const unsigned short* W2t = mlp ? Cw2t : Pw2t;
    const float* b1 = mlp ? b1C : b1P;
    const float* b2 = mlp ? b2C : b2P;
    unsigned short* Sout = mlp ? ScE : SpE;
    const int* pos = mlp ? posC : posP;
    // write O1 = relu(acc + b1)
#pragma unroll
    for (int nn = 0; nn < 2; ++nn) {
      int col = w * 32 + nn * 16 + ln;
      float bb = b1[col];
#pragma unroll
      for (int m = 0; m < 4; ++m)
#pragma unroll
        for (int r = 0; r < 4; ++r) {
          float v = mlp ? accC[m][nn][r] : accP[m][nn][r];
          O1[(m * 16 + quad * 4 + r) * 264 + col] = f2bf(fmaxf(v + bb, 0.f));
        }
    }
    __syncthreads();
    // layer 2: wave w -> cols [w*16, w*16+16)
    f32x4 acc2[4];
#pragma unroll
    for (int m = 0; m < 4; ++m) acc2[m] = {0.f, 0.f, 0.f, 0.f};
#pragma unroll
    for (int kt = 0; kt < 8; ++kt) {
      short8 b = *(const short8*)(W2t + (size_t)(w * 16 + ln) * 256 + kt * 32 + qo);
#pragma unroll
      for (int m = 0; m < 4; ++m) {
        short8 a = *(const short8*)(O1 + (m * 16 + ln) * 264 + kt * 32 + qo);
        acc2[m] = mfma16(a, b, acc2[m]);
      }
    }
    __syncthreads();  // O1 reads done -> safe to overwrite with repack
    {
      int col = w * 16 + ln;
      float bb = b2[col];
#pragma unroll
      for (int m = 0; m < 4; ++m)
#pragma unroll
        for (int r = 0; r < 4; ++r)
          O1[(m * 16 + quad * 4 + r) * 264 + col] = f2bf(fmaxf(acc2[m][r] + bb, 0.f));
    }
    __syncthreads();
    // scatter rows to CSR positions: 8 thr/row x 16 cols (256B/row contiguous)
    if (vrow) {
      int dpos = pos[ge];
      const unsigned short* srow = O1 + rl * 264 + part * 16;
      ushort4* dst = (ushort4*)(Sout + (size_t)dpos * DD + part * 16);
#pragma unroll
      for (int i = 0; i < 4; ++i) dst[i] = *(const ushort4*)(srow + i * 4);
    }
    __syncthreads();  // store LDS-reads done before next mlp overwrites O1
  }
}

// ---- cooperative node kernel: CSR gather-mean (contiguous rows, no chase),
// build [h|S_p|S_c], MLP_A (K=384), residual add. 512 thr, O1 overlaid on A.
// Reads h from bf16 mirror when available; writes updated mirror.
__global__ __launch_bounds__(512, 4) void node_kernel(
    float* __restrict__ hidden, unsigned short* __restrict__ hbf,
    const unsigned short* __restrict__ SpE, const unsigned short* __restrict__ ScE,
    const int* __restrict__ offP, const int* __restrict__ degP,
    const int* __restrict__ offC, const int* __restrict__ degC,
    const float* __restrict__ rootM, const float* __restrict__ leafM,
    const float* __restrict__ startT, const float* __restrict__ endT,
    const unsigned short* __restrict__ W1t, const unsigned short* __restrict__ W2t,
    const float* __restrict__ b1, const float* __restrict__ b2, int n) {
  __shared__ __align__(16) unsigned short A[64 * 392];
  int t = threadIdx.x;
  int w = t >> 6, lane = t & 63, ln = lane & 15, quad = lane >> 4, qo = quad * 8;
  long tile0 = (long)blockIdx.x * 64;
  int rl = t >> 3, part = t & 7;
  int c0 = part * 16;
  long gr = tile0 + rl;
  long g = (gr < n) ? gr : 0;
  unsigned short* arow = A + rl * 392;
  if (hbf) {  // h cols from bf16 mirror (2x fewer bytes, no conversion)
    const unsigned short* hrowb = hbf + (size_t)g * DD + c0;
    *(short8*)(arow + c0)     = *(const short8*)(hrowb);
    *(short8*)(arow + c0 + 8) = *(const short8*)(hrowb + 8);
  } else {
    const float* hrow = hidden + (size_t)g * DD + c0;
#pragma unroll
    for (int i = 0; i < 4; ++i) {
      float4 h = *(const float4*)(hrow + i * 4);
      *(ushort4*)(arow + c0 + i * 4) = make_ushort4(f2bf(h.x), f2bf(h.y), f2bf(h.z), f2bf(h.w));
    }
  }
  {  // S_p mean: contiguous CSR rows
    int off = offP[g], dg = degP[g];
    float s[16];
#pragma unroll
    for (int i = 0; i < 16; ++i) s[i] = 0.f;
    for (int j = 0; j < dg; ++j) {
      const unsigned short* rr = SpE + (size_t)(off + j) * DD + c0;
#pragma unroll
      for (int i = 0; i < 4; ++i) {
        ushort4 u = *(const ushort4*)(rr + i * 4);
        s[i * 4 + 0] += bf2f(u.x); s[i * 4 + 1] += bf2f(u.y);
        s[i * 4 + 2] += bf2f(u.z); s[i * 4 + 3] += bf2f(u.w);
      }
    }
    float ip = 1.f / fmaxf((float)dg, 1.f);
    float rm = rootM[g];
#pragma unroll
    for (int i = 0; i < 4; ++i) {
      float4 st = *(const float4*)(startT + c0 + i * 4);
      *(ushort4*)(arow + 128 + c0 + i * 4) = make_ushort4(
          f2bf(s[i * 4 + 0] * ip + rm * st.x), f2bf(s[i * 4 + 1] * ip + rm * st.y),
          f2bf(s[i * 4 + 2] * ip + rm * st.z), f2bf(s[i * 4 + 3] * ip + rm * st.w));
    }
  }
  {  // S_c mean
    int off = offC[g], dg = degC[g];
    float s[16];
#pragma unroll
    for (int i = 0; i < 16; ++i) s[i] = 0.f;
    for (int j = 0; j < dg; ++j) {
      const unsigned short* rr = ScE + (size_t)(off + j) * DD + c0;
#pragma unroll
      for (int i = 0; i < 4; ++i) {
        ushort4 u = *(const ushort4*)(rr + i * 4);
        s[i * 4 + 0] += bf2f(u.x); s[i * 4 + 1] += bf2f(u.y);
        s[i * 4 + 2] += bf2f(u.z); s[i * 4 + 3] += bf2f(u.w);
      }
    }
    float ic = 1.f / fmaxf((float)dg, 1.f);
    float lm = leafM[g];
#pragma unroll
    for (int i = 0; i < 4; ++i) {
      float4 et = *(const float4*)(endT + c0 + i * 4);
      *(ushort4*)(arow + 256 + c0 + i * 4) = make_ushort4(
          f2bf(s[i * 4 + 0] * ic + lm * et.x), f2bf(s[i * 4 + 1] * ic + lm * et.y),
          f2bf(s[i * 4 + 2] * ic + lm * et.z), f2bf(s[i * 4 + 3] * ic + lm * et.w));
    }
  }
  __syncthreads();
  // layer 1 (K=384): wave w -> cols [w*32, w*32+32)
  f32x4 acc[4][2];
#pragma unroll
  for (int m = 0; m < 4; ++m) {
    acc[m][0] = {0.f, 0.f, 0.f, 0.f}; acc[m][1] = {0.f, 0.f, 0.f, 0.f};
  }
#pragma unroll
  for (int kt = 0; kt < 12; ++kt) {
    short8 a[4];
#pragma unroll
    for (int m = 0; m < 4; ++m)
      a[m] = *(const short8*)(A + (m * 16 + ln) * 392 + kt * 32 + qo);
#pragma unroll
    for (int nn = 0; nn < 2; ++nn) {
      short8 b = *(const short8*)(W1t + (size_t)(w * 32 + nn * 16 + ln) * 384 + kt * 32 + qo);
#pragma unroll
      for (int m = 0; m < 4; ++m) acc[m][nn] = mfma16(a[m], b, acc[m][nn]);
    }
  }
  __syncthreads();  // all A reads done -> overlay O1 into A storage
#pragma unroll
  for (int nn = 0; nn < 2; ++nn) {
    int col = w * 32 + nn * 16 + ln;
    float bb = b1[col];
#pragma unroll
    for (int m = 0; m < 4; ++m)
#pragma unroll
      for (int r = 0; r < 4; ++r)
        A[(m * 16 + quad * 4 + r) * 392 + col] = f2bf(fmaxf(acc[m][nn][r] + bb, 0.f));
  }
  __syncthreads();
  // layer 2 (K=256): wave w -> cols [w*16, w*16+16)
  f32x4 acc2[4];
#pragma unroll
  for (int m = 0; m < 4; ++m) acc2[m] = {0.f, 0.f, 0.f, 0.f};
#pragma unroll
  for (int kt = 0; kt < 8; ++kt) {
    short8 b = *(const short8*)(W2t + (size_t)(w * 16 + ln) * 256 + kt * 32 + qo);
#pragma unroll
    for (int m = 0; m < 4; ++m) {
      short8 a = *(const short8*)(A + (m * 16 + ln) * 392 + kt * 32 + qo);
      acc2[m] = mfma16(a, b, acc2[m]);
    }
  }
  __syncthreads();  // O1 reads done -> overlay fp32 repack (keeps residual in fp32)
  {
    int col = w * 16 + ln;
    float bb = b2[col];
#pragma unroll
    for (int m = 0; m < 4; ++m)
#pragma unroll
      for (int r = 0; r < 4; ++r)
        ((float*)(A + (size_t)(m * 16 + quad * 4 + r) * 392))[col] =
            fmaxf(acc2[m][r] + bb, 0.f);
  }
  __syncthreads();
  if (gr < n) {
    const float* F = (const float*)(A + (size_t)rl * 392);
    float* hrow = hidden + (size_t)gr * DD + c0;
    unsigned short* brow = hbf ? hbf + (size_t)gr * DD + c0 : nullptr;
#pragma unroll
    for (int i = 0; i < 4; ++i) {
      float4 v = *(const float4*)(F + c0 + i * 4);
      float4 h = *(const float4*)(hrow + i * 4);
      h.x += v.x; h.y += v.y; h.z += v.z; h.w += v.w;
      *(float4*)(hrow + i * 4) = h;
      if (brow)
        *(ushort4*)(brow + i * 4) = make_ushort4(f2bf(h.x), f2bf(h.y), f2bf(h.z), f2bf(h.w));
    }
  }
}

extern "C" void kernel_launch(void* const* d_in, const int* in_sizes, int n_in,
                              void* d_out, int out_size, void* d_ws, size_t ws_size,
                              hipStream_t stream) {
  const float* batch  = (const float*)d_in[0];
  const int*   selfI  = (const int*)d_in[1];
  const int*   parI   = (const int*)d_in[2];
  const float* rootM  = (const float*)d_in[3];
  const float* leafM  = (const float*)d_in[4];
  const float* startT = (const float*)d_in[5];
  const float* endT   = (const float*)d_in[6];
  const float* Vw1 = (const float*)d_in[7],  *Vb1 = (const float*)d_in[8];
  const float* Vw2 = (const float*)d_in[9],  *Vb2 = (const float*)d_in[10];
  const float* Ew1 = (const float*)d_in[11], *Eb1 = (const float*)d_in[12];
  const float* Ew2 = (const float*)d_in[13], *Eb2 = (const float*)d_in[14];
  const float* Pw1 = (const float*)d_in[15], *Pb1 = (const float*)d_in[16];
  const float* Pw2 = (const float*)d_in[17], *Pb2 = (const float*)d_in[18];
  const float* Cw1 = (const float*)d_in[19], *Cb1 = (const float*)d_in[20];
  const float* Cw2 = (const float*)d_in[21], *Cb2 = (const float*)d_in[22];
  const float* Aw1 = (const float*)d_in[23], *Ab1 = (const float*)d_in[24];
  const float* Aw2 = (const float*)d_in[25], *Ab2 = (const float*)d_in[26];

  const int N = in_sizes[3];
  const int E = in_sizes[1];
  float* out = (float*)d_out;

  char* p = (char*)d_ws;
  auto nxt = [&](size_t sz) { char* r = p; p += (sz + 255) & ~(size_t)255; return r; };
  unsigned short* SpE = (unsigned short*)nxt((size_t)E * DD * 2);
  unsigned short* ScE = (unsigned short*)nxt((size_t)E * DD * 2);
  int* degP = (int*)nxt((size_t)N * 4);
  int* degC = (int*)nxt((size_t)N * 4);
  int* offP = (int*)nxt((size_t)N * 4);
  int* offC = (int*)nxt((size_t)N * 4);
  int* curP = (int*)nxt((size_t)N * 4);
  int* curC = (int*)nxt((size_t)N * 4);
  int* posP = (int*)nxt((size_t)E * 4);
  int* posC = (int*)nxt((size_t)E * 4);
  int* partA = (int*)nxt(4096);
  int* partB = (int*)nxt(4096);
  unsigned short* Vw1t = (unsigned short*)nxt((size_t)128 * 256 * 2);
  unsigned short* Vw2t = (unsigned short*)nxt((size_t)256 * 128 * 2);
  unsigned short* Pw1t = (unsigned short*)nxt((size_t)256 * 256 * 2);
  unsigned short* Pw2t = (unsigned short*)nxt((size_t)256 * 128 * 2);
  unsigned short* Cw1t = (unsigned short*)nxt((size_t)256 * 256 * 2);
  unsigned short* Cw2t = (unsigned short*)nxt((size_t)256 * 128 * 2);
  unsigned short* Aw1t = (unsigned short*)nxt((size_t)384 * 256 * 2);
  unsigned short* Aw2t = (unsigned short*)nxt((size_t)256 * 128 * 2);
  float* b1P = (float*)nxt(256 * 4);
  float* b1C = (float*)nxt(256 * 4);
  // bf16 mirror of hidden (allocated last; optional — runtime ws_size guard)
  unsigned short* Hbf = (unsigned short*)nxt((size_t)N * DD * 2);
  if ((size_t)(p - (char*)d_ws) > ws_size) Hbf = nullptr;

  hipMemsetAsync(degP, 0, (size_t)N * 4, stream);
  hipMemsetAsync(degC, 0, (size_t)N * 4, stream);

  auto blk = [](int total) { return dim3((total + 255) / 256); };
  wconv<<<blk(128 * 256), 256, 0, stream>>>(Vw1, Vw1t, 128, 256, 0);
  wconv<<<blk(256 * 128), 256, 0, stream>>>(Vw2, Vw2t, 256, 128, 0);
  wconv<<<blk(256 * 256), 256, 0, stream>>>(Pw1, Pw1t, 256, 256, 128);  // half-swap
  wconv<<<blk(256 * 128), 256, 0, stream>>>(Pw2, Pw2t, 256, 128, 0);
  wconv<<<blk(256 * 256), 256, 0, stream>>>(Cw1, Cw1t, 256, 256, 0);
  wconv<<<blk(256 * 128), 256, 0, stream>>>(Cw2, Cw2t, 256, 128, 0);
  wconv<<<blk(384 * 256), 256, 0, stream>>>(Aw1, Aw1t, 384, 256, 0);
  wconv<<<blk(256 * 128), 256, 0, stream>>>(Aw2, Aw2t, 256, 128, 0);

  prep_bias<<<1, 256, 0, stream>>>(Ew1, Eb1, Ew2, Eb2, Pw1, Pb1, Cw1, Cb1, b1P, b1C);
  count_k<<<blk(E), 256, 0, stream>>>(selfI, parI, degP, degC, E);

  int NB = (N + 1023) / 1024;
  scan1<<<NB, 256, 0, stream>>>(degP, offP, partA, N);
  scan1<<<NB, 256, 0, stream>>>(degC, offC, partB, N);
  scan2<<<1, 256, 0, stream>>>(partA, NB);
  scan2<<<1, 256, 0, stream>>>(partB, NB);
  scan3<<<blk(N), 256, 0, stream>>>(offP, partA, N);
  scan3<<<blk(N), 256, 0, stream>>>(offC, partB, N);
  copy2<<<blk(N), 256, 0, stream>>>(offP, curP, offC, curC, N);
  pos_k<<<blk(E), 256, 0, stream>>>(selfI, parI, curP, curC, posP, posC, E);

  dim3 gN((N + 63) / 64), gE((E + 63) / 64);
  v_kernel<<<gN, 512, 0, stream>>>(batch, Vw1t, Vw2t, Vb1, Vb2, out, Hbf, N);

  for (int hop = 0; hop < 3; ++hop) {
    edge_kernel<<<gE, 512, 0, stream>>>(out, Hbf, selfI, parI, posP, posC,
                                        Pw1t, Pw2t, Cw1t, Cw2t, b1P, b1C, Pb2, Cb2,
                                        SpE, ScE, E);
    node_kernel<<<gN, 512, 0, stream>>>(out, Hbf, SpE, ScE, offP, degP, offC, degC,
                                        rootM, leafM, startT, endT,
                                        Aw1t, Aw2t, Ab1, Ab2, N);
  }
}

// Round 4
// 1840.818 us; speedup vs baseline: 1.4108x; 1.0230x over previous
//
#include <hip/hip_runtime.h>

typedef __attribute__((ext_vector_type(8))) short short8;
typedef __attribute__((ext_vector_type(4))) float f32x4;

#define DD 128
#define HH 256

__device__ __forceinline__ unsigned short f2bf(float f) {
  unsigned int u = __float_as_uint(f);
  u += 0x7fffu + ((u >> 16) & 1u);
  return (unsigned short)(u >> 16);
}
__device__ __forceinline__ float bf2f(unsigned short s) {
  return __uint_as_float(((unsigned int)s) << 16);
}
__device__ __forceinline__ f32x4 mfma16(short8 a, short8 b, f32x4 c) {
  return __builtin_amdgcn_mfma_f32_16x16x32_bf16(a, b, c, 0, 0, 0);
}

// ---- fused weight convert for all 8 matrices: dst[n][k] = bf16(src[(k+kswap)%K][n])
__global__ void wconv_all(const float* __restrict__ s0, const float* __restrict__ s1,
                          const float* __restrict__ s2, const float* __restrict__ s3,
                          const float* __restrict__ s4, const float* __restrict__ s5,
                          const float* __restrict__ s6, const float* __restrict__ s7,
                          unsigned short* __restrict__ d0, unsigned short* __restrict__ d1,
                          unsigned short* __restrict__ d2, unsigned short* __restrict__ d3,
                          unsigned short* __restrict__ d4, unsigned short* __restrict__ d5,
                          unsigned short* __restrict__ d6, unsigned short* __restrict__ d7) {
  int id = blockIdx.x * 256 + threadIdx.x;
  const float* src; unsigned short* dst; int K, Nout, kswap = 0, base;
  if (id < 32768)       { src = s0; dst = d0; K = 128; Nout = 256; base = 0; }
  else if (id < 65536)  { src = s1; dst = d1; K = 256; Nout = 128; base = 32768; }
  else if (id < 131072) { src = s2; dst = d2; K = 256; Nout = 256; base = 65536; kswap = 128; }
  else if (id < 163840) { src = s3; dst = d3; K = 256; Nout = 128; base = 131072; }
  else if (id < 229376) { src = s4; dst = d4; K = 256; Nout = 256; base = 163840; }
  else if (id < 262144) { src = s5; dst = d5; K = 256; Nout = 128; base = 229376; }
  else if (id < 360448) { src = s6; dst = d6; K = 384; Nout = 256; base = 262144; }
  else if (id < 393216) { src = s7; dst = d7; K = 256; Nout = 128; base = 360448; }
  else return;
  int lid = id - base;
  int n = lid / K, k = lid - n * K;
  int ks = k + kswap; if (ks >= K) ks -= K;
  dst[n * K + k] = f2bf(src[(size_t)ks * Nout + n]);
}

// ---- edge vectors + fold edge constants into layer-1 biases (1 block, 256 thr)
__global__ void prep_bias(const float* __restrict__ Ew1, const float* __restrict__ Eb1,
                          const float* __restrict__ Ew2, const float* __restrict__ Eb2,
                          const float* __restrict__ Pw1, const float* __restrict__ Pb1,
                          const float* __restrict__ Cw1, const float* __restrict__ Cb1,
                          float* __restrict__ b1P, float* __restrict__ b1C) {
  __shared__ float h1[HH], h0[HH], ein[DD], eout[DD];
  int t = threadIdx.x;
  h1[t] = fmaxf(Ew1[t] + Eb1[t], 0.f);
  h0[t] = fmaxf(Eb1[t], 0.f);
  __syncthreads();
  if (t < DD) {
    float s1 = Eb2[t], s0 = Eb2[t];
    for (int j = 0; j < HH; ++j) { s1 += h1[j] * Ew2[j * DD + t]; s0 += h0[j] * Ew2[j * DD + t]; }
    ein[t]  = fmaxf(s1, 0.f);
    eout[t] = fmaxf(s0, 0.f);
  }
  __syncthreads();
  float bp = Pb1[t], bc = Cb1[t];
  for (int d = 0; d < DD; ++d) {
    bp += eout[d] * Pw1[(size_t)(256 + d) * HH + t];
    bc += ein[d]  * Cw1[(size_t)(256 + d) * HH + t];
  }
  b1P[t] = bp; b1C[t] = bc;
}

// ---- CSR build: degree count, paired exclusive scans, per-edge position
__global__ void count_k(const int* __restrict__ selfI, const int* __restrict__ parI,
                        int* degP, int* degC, int E) {
  int id = blockIdx.x * 256 + threadIdx.x;
  if (id < E) { atomicAdd(&degP[selfI[id]], 1); atomicAdd(&degC[parI[id]], 1); }
}

__global__ void scan1_2(const int* __restrict__ srcA, int* __restrict__ dstA, int* __restrict__ partA,
                        const int* __restrict__ srcB, int* __restrict__ dstB, int* __restrict__ partB,
                        int n) {
  const int* src = blockIdx.y ? srcB : srcA;
  int* dst = blockIdx.y ? dstB : dstA;
  int* part = blockIdx.y ? partB : partA;
  __shared__ int sh[256];
  int t = threadIdx.x;
  int base = blockIdx.x * 1024 + t * 4;
  int v0 = base + 0 < n ? src[base + 0] : 0;
  int v1 = base + 1 < n ? src[base + 1] : 0;
  int v2 = base + 2 < n ? src[base + 2] : 0;
  int v3 = base + 3 < n ? src[base + 3] : 0;
  int tsum = v0 + v1 + v2 + v3;
  sh[t] = tsum;
  __syncthreads();
  for (int off = 1; off < 256; off <<= 1) {
    int y = (t >= off) ? sh[t - off] : 0;
    __syncthreads();
    if (t >= off) sh[t] += y;
    __syncthreads();
  }
  int ex = sh[t] - tsum;
  if (base + 0 < n) dst[base + 0] = ex;
  if (base + 1 < n) dst[base + 1] = ex + v0;
  if (base + 2 < n) dst[base + 2] = ex + v0 + v1;
  if (base + 3 < n) dst[base + 3] = ex + v0 + v1 + v2;
  if (t == 255) part[blockIdx.x] = sh[255];
}

__global__ void scan2_2(int* __restrict__ partA, int* __restrict__ partB, int m) {
  int* part = blockIdx.x ? partB : partA;
  __shared__ int sh[256];
  int t = threadIdx.x;
  int carry = 0;
  for (int base = 0; base < m; base += 256) {
    int v = (base + t < m) ? part[base + t] : 0;
    sh[t] = v;
    __syncthreads();
    for (int off = 1; off < 256; off <<= 1) {
      int y = (t >= off) ? sh[t - off] : 0;
      __syncthreads();
      if (t >= off) sh[t] += y;
      __syncthreads();
    }
    if (base + t < m) part[base + t] = carry + sh[t] - v;
    int tot = sh[255];
    __syncthreads();
    carry += tot;
  }
}

// scan3 for both arrays + copy into cur*
__global__ void scan3copy(int* __restrict__ offP, const int* __restrict__ partA, int* __restrict__ curP,
                          int* __restrict__ offC, const int* __restrict__ partB, int* __restrict__ curC,
                          int n) {
  int i = blockIdx.x * 256 + threadIdx.x;
  if (i < n) {
    int a = offP[i] + partA[i >> 10];
    int b = offC[i] + partB[i >> 10];
    offP[i] = a; curP[i] = a;
    offC[i] = b; curC[i] = b;
  }
}

__global__ void pos_k(const int* __restrict__ selfI, const int* __restrict__ parI,
                      int* curP, int* curC, int* posP, int* posC, int E) {
  int e = blockIdx.x * 256 + threadIdx.x;
  if (e < E) {
    posP[e] = atomicAdd(&curP[selfI[e]], 1);
    posC[e] = atomicAdd(&curC[parI[e]], 1);
  }
}

// ---- CSR-P reorder: slot k = posP[e] (absolute CSR-P position, bijective).
// Edge tiles then stream selfS (sorted -> near-coalesced gathers), write SpE
// contiguously at slot k, and keep only parent-gather + C-scatter random.
__global__ void reorder_k(const int* __restrict__ selfI, const int* __restrict__ parI,
                          const int* __restrict__ posP, const int* __restrict__ posC,
                          int* __restrict__ selfS, int* __restrict__ parS,
                          int* __restrict__ posCS, int E) {
  int e = blockIdx.x * 256 + threadIdx.x;
  if (e < E) {
    int slot = posP[e];
    selfS[slot] = selfI[e];
    parS[slot] = parI[e];
    posCS[slot] = posC[e];
  }
}

// ---- cooperative MLP_V: 512 thr / 8 waves, waves split N-dim.
// K=128 -> 256 -> 128. Also emits bf16 mirror of hidden (for edge gathers).
__global__ __launch_bounds__(512, 4) void v_kernel(
    const float* __restrict__ x, const unsigned short* __restrict__ W1t,
    const unsigned short* __restrict__ W2t, const float* __restrict__ b1,
    const float* __restrict__ b2, float* __restrict__ hidden,
    unsigned short* __restrict__ hbf, int n) {
  __shared__ __align__(16) unsigned short A[64 * 136];
  __shared__ __align__(16) unsigned short O1[64 * 264];
  int t = threadIdx.x;
  int w = t >> 6, lane = t & 63, ln = lane & 15, quad = lane >> 4, qo = quad * 8;
  long tile0 = (long)blockIdx.x * 64;
  int rl = t >> 3, part = t & 7;
  int c0 = part * 16;
  long gr = tile0 + rl;
  const float* src = x + (size_t)(gr < n ? gr : 0) * DD + c0;
  unsigned short* arow = A + rl * 136 + c0;
#pragma unroll
  for (int i = 0; i < 4; ++i) {
    float4 v = *(const float4*)(src + i * 4);
    *(ushort4*)(arow + i * 4) = make_ushort4(f2bf(v.x), f2bf(v.y), f2bf(v.z), f2bf(v.w));
  }
  __syncthreads();
  // layer 1 (K=128): wave w -> cols [w*32, w*32+32)
  f32x4 acc[4][2];
#pragma unroll
  for (int m = 0; m < 4; ++m) {
    acc[m][0] = {0.f, 0.f, 0.f, 0.f}; acc[m][1] = {0.f, 0.f, 0.f, 0.f};
  }
#pragma unroll
  for (int kt = 0; kt < 4; ++kt) {
    short8 a[4];
#pragma unroll
    for (int m = 0; m < 4; ++m)
      a[m] = *(const short8*)(A + (m * 16 + ln) * 136 + kt * 32 + qo);
#pragma unroll
    for (int nn = 0; nn < 2; ++nn) {
      short8 b = *(const short8*)(W1t + (size_t)(w * 32 + nn * 16 + ln) * 128 + kt * 32 + qo);
#pragma unroll
      for (int m = 0; m < 4; ++m) acc[m][nn] = mfma16(a[m], b, acc[m][nn]);
    }
  }
#pragma unroll
  for (int nn = 0; nn < 2; ++nn) {
    int col = w * 32 + nn * 16 + ln;
    float bb = b1[col];
#pragma unroll
    for (int m = 0; m < 4; ++m)
#pragma unroll
      for (int r = 0; r < 4; ++r)
        O1[(m * 16 + quad * 4 + r) * 264 + col] = f2bf(fmaxf(acc[m][nn][r] + bb, 0.f));
  }
  __syncthreads();
  // layer 2 (K=256): wave w -> cols [w*16, w*16+16)
  f32x4 acc2[4];
#pragma unroll
  for (int m = 0; m < 4; ++m) acc2[m] = {0.f, 0.f, 0.f, 0.f};
#pragma unroll
  for (int kt = 0; kt < 8; ++kt) {
    short8 b = *(const short8*)(W2t + (size_t)(w * 16 + ln) * 256 + kt * 32 + qo);
#pragma unroll
    for (int m = 0; m < 4; ++m) {
      short8 a = *(const short8*)(O1 + (m * 16 + ln) * 264 + kt * 32 + qo);
      acc2[m] = mfma16(a, b, acc2[m]);
    }
  }
  {
    int col = w * 16 + ln;
    float bb = b2[col];
#pragma unroll
    for (int m = 0; m < 4; ++m)
#pragma unroll
      for (int r = 0; r < 4; ++r) {
        long gr2 = tile0 + m * 16 + quad * 4 + r;
        if (gr2 < n) {
          float v = fmaxf(acc2[m][r] + bb, 0.f);
          hidden[gr2 * DD + col] = v;
          if (hbf) hbf[gr2 * DD + col] = f2bf(v);
        }
      }
  }
}

// ---- cooperative edge kernel (CSR-P ordered): 512 thr / 8 waves, M=64 slots.
// Row k: hs = h[selfS[k]] (sorted gather), hp = h[parS[k]] (random gather).
// P-output row -> SpE[k] (CONTIGUOUS). C-output row -> ScE[posCS[k]] (random).
__global__ __launch_bounds__(512, 4) void edge_kernel(
    const float* __restrict__ hidden, const unsigned short* __restrict__ hbf,
    const int* __restrict__ selfS, const int* __restrict__ parS,
    const int* __restrict__ posCS,
    const unsigned short* __restrict__ Pw1t, const unsigned short* __restrict__ Pw2t,
    const unsigned short* __restrict__ Cw1t, const unsigned short* __restrict__ Cw2t,
    const float* __restrict__ b1P, const float* __restrict__ b1C,
    const float* __restrict__ b2P, const float* __restrict__ b2C,
    unsigned short* __restrict__ SpE, unsigned short* __restrict__ ScE, int E) {
  __shared__ __align__(16) unsigned short A[64 * 264];   // [hs|hp] bf16 tile
  __shared__ __align__(16) unsigned short O1[64 * 264];  // layer-1 out / repack buf
  int t = threadIdx.x;
  int w = t >> 6, lane = t & 63, ln = lane & 15, quad = lane >> 4, qo = quad * 8;
  long tile0 = (long)blockIdx.x * 64;
  int rl = t >> 3, part = t & 7;
  long ge = tile0 + rl;
  bool vrow = ge < E;
  int si = vrow ? selfS[ge] : 0;
  int pi = vrow ? parS[ge] : 0;
  unsigned short* dstA = A + rl * 264 + part * 32;
  if (hbf) {
    const unsigned short* srcb = (part < 4) ? (hbf + (size_t)si * DD + part * 32)
                                            : (hbf + (size_t)pi * DD + (part - 4) * 32);
#pragma unroll
    for (int i = 0; i < 4; ++i)
      *(short8*)(dstA + i * 8) = *(const short8*)(srcb + i * 8);
  } else {
    const float* src = (part < 4) ? (hidden + (size_t)si * DD + part * 32)
                                  : (hidden + (size_t)pi * DD + (part - 4) * 32);
#pragma unroll
    for (int i = 0; i < 8; ++i) {
      float4 v = *(const float4*)(src + i * 4);
      *(ushort4*)(dstA + i * 4) = make_ushort4(f2bf(v.x), f2bf(v.y), f2bf(v.z), f2bf(v.w));
    }
  }
  __syncthreads();

  // fused layer 1 for P and C: one a[4] read feeds 16 MFMAs
  f32x4 accP[4][2], accC[4][2];
#pragma unroll
  for (int m = 0; m < 4; ++m) {
    accP[m][0] = {0.f, 0.f, 0.f, 0.f}; accP[m][1] = {0.f, 0.f, 0.f, 0.f};
    accC[m][0] = {0.f, 0.f, 0.f, 0.f}; accC[m][1] = {0.f, 0.f, 0.f, 0.f};
  }
#pragma unroll
  for (int kt = 0; kt < 8; ++kt) {
    short8 a[4];
#pragma unroll
    for (int m = 0; m < 4; ++m)
      a[m] = *(const short8*)(A + (m * 16 + ln) * 264 + kt * 32 + qo);
#pragma unroll
    for (int nn = 0; nn < 2; ++nn) {
      short8 bp = *(const short8*)(Pw1t + (size_t)(w * 32 + nn * 16 + ln) * 256 + kt * 32 + qo);
      short8 bc = *(const short8*)(Cw1t + (size_t)(w * 32 + nn * 16 + ln) * 256 + kt * 32 + qo);
#pragma unroll
      for (int m = 0; m < 4; ++m) {
        accP[m][nn] = mfma16(a[m], bp, accP[m][nn]);
        accC[m][nn] = mfma16(a[m], bc, accC[m][nn]);
      }
    }
  }
  // no barrier: A and O1 are distinct buffers; O1 has no readers yet

#pragma unroll
  for (int mlp = 0; mlp < 2; ++mlp) {
    const unsigned short* W2t = mlp ? Cw2t : Pw2t;
    const float* b1 = mlp ? b1C : b1P;
    const float* b2 = mlp ? b2C : b2P;
    unsigned short* Sout = mlp ? ScE : SpE;
    // write O1 = relu(acc + b1)
#pragma unroll
    for (int nn = 0; nn < 2; ++nn) {
      int col = w * 32 + nn * 16 + ln;
      float bb = b1[col];
#pragma unroll
      for (int m = 0; m < 4; ++m)
#pragma unroll
        for (int r = 0; r < 4; ++r) {
          float v = mlp ? accC[m][nn][r] : accP[m][nn][r];
          O1[(m * 16 + quad * 4 + r) * 264 + col] = f2bf(fmaxf(v + bb, 0.f));
        }
    }
    __syncthreads();
    // layer 2: wave w -> cols [w*16, w*16+16)
    f32x4 acc2[4];
#pragma unroll
    for (int m = 0; m < 4; ++m) acc2[m] = {0.f, 0.f, 0.f, 0.f};
#pragma unroll
    for (int kt = 0; kt < 8; ++kt) {
      short8 b = *(const short8*)(W2t + (size_t)(w * 16 + ln) * 256 + kt * 32 + qo);
#pragma unroll
      for (int m = 0; m < 4; ++m) {
        short8 a = *(const short8*)(O1 + (m * 16 + ln) * 264 + kt * 32 + qo);
        acc2[m] = mfma16(a, b, acc2[m]);
      }
    }
    __syncthreads();  // O1 reads done -> safe to overwrite with repack
    {
      int col = w * 16 + ln;
      float bb = b2[col];
#pragma unroll
      for (int m = 0; m < 4; ++m)
#pragma unroll
        for (int r = 0; r < 4; ++r)
          O1[(m * 16 + quad * 4 + r) * 264 + col] = f2bf(fmaxf(acc2[m][r] + bb, 0.f));
    }
    __syncthreads();
    // store rows: P -> contiguous slot ge; C -> CSR-C position (random)
    if (vrow) {
      size_t dpos = mlp ? (size_t)posCS[ge] : (size_t)ge;
      const unsigned short* srow = O1 + rl * 264 + part * 16;
      ushort4* dst = (ushort4*)(Sout + dpos * DD + part * 16);
#pragma unroll
      for (int i = 0; i < 4; ++i) dst[i] = *(const ushort4*)(srow + i * 4);
    }
    __syncthreads();  // store LDS-reads done before next mlp overwrites O1
  }
}

// ---- cooperative node kernel: CSR gather-mean (contiguous rows, no chase),
// build [h|S_p|S_c], MLP_A (K=384), residual add. 512 thr, O1 overlaid on A.
// Reads h from bf16 mirror when available; writes updated mirror.
__global__ __launch_bounds__(512, 4) void node_kernel(
    float* __restrict__ hidden, unsigned short* __restrict__ hbf,
    const unsigned short* __restrict__ SpE, const unsigned short* __restrict__ ScE,
    const int* __restrict__ offP, const int* __restrict__ degP,
    const int* __restrict__ offC, const int* __restrict__ degC,
    const float* __restrict__ rootM, const float* __restrict__ leafM,
    const float* __restrict__ startT, const float* __restrict__ endT,
    const unsigned short* __restrict__ W1t, const unsigned short* __restrict__ W2t,
    const float* __restrict__ b1, const float* __restrict__ b2, int n) {
  __shared__ __align__(16) unsigned short A[64 * 392];
  int t = threadIdx.x;
  int w = t >> 6, lane = t & 63, ln = lane & 15, quad = lane >> 4, qo = quad * 8;
  long tile0 = (long)blockIdx.x * 64;
  int rl = t >> 3, part = t & 7;
  int c0 = part * 16;
  long gr = tile0 + rl;
  long g = (gr < n) ? gr : 0;
  unsigned short* arow = A + rl * 392;
  if (hbf) {  // h cols from bf16 mirror (2x fewer bytes, no conversion)
    const unsigned short* hrowb = hbf + (size_t)g * DD + c0;
    *(short8*)(arow + c0)     = *(const short8*)(hrowb);
    *(short8*)(arow + c0 + 8) = *(const short8*)(hrowb + 8);
  } else {
    const float* hrow = hidden + (size_t)g * DD + c0;
#pragma unroll
    for (int i = 0; i < 4; ++i) {
      float4 h = *(const float4*)(hrow + i * 4);
      *(ushort4*)(arow + c0 + i * 4) = make_ushort4(f2bf(h.x), f2bf(h.y), f2bf(h.z), f2bf(h.w));
    }
  }
  {  // S_p mean: contiguous CSR rows
    int off = offP[g], dg = degP[g];
    float s[16];
#pragma unroll
    for (int i = 0; i < 16; ++i) s[i] = 0.f;
    for (int j = 0; j < dg; ++j) {
      const unsigned short* rr = SpE + (size_t)(off + j) * DD + c0;
#pragma unroll
      for (int i = 0; i < 4; ++i) {
        ushort4 u = *(const ushort4*)(rr + i * 4);
        s[i * 4 + 0] += bf2f(u.x); s[i * 4 + 1] += bf2f(u.y);
        s[i * 4 + 2] += bf2f(u.z); s[i * 4 + 3] += bf2f(u.w);
      }
    }
    float ip = 1.f / fmaxf((float)dg, 1.f);
    float rm = rootM[g];
#pragma unroll
    for (int i = 0; i < 4; ++i) {
      float4 st = *(const float4*)(startT + c0 + i * 4);
      *(ushort4*)(arow + 128 + c0 + i * 4) = make_ushort4(
          f2bf(s[i * 4 + 0] * ip + rm * st.x), f2bf(s[i * 4 + 1] * ip + rm * st.y),
          f2bf(s[i * 4 + 2] * ip + rm * st.z), f2bf(s[i * 4 + 3] * ip + rm * st.w));
    }
  }
  {  // S_c mean
    int off = offC[g], dg = degC[g];
    float s[16];
#pragma unroll
    for (int i = 0; i < 16; ++i) s[i] = 0.f;
    for (int j = 0; j < dg; ++j) {
      const unsigned short* rr = ScE + (size_t)(off + j) * DD + c0;
#pragma unroll
      for (int i = 0; i < 4; ++i) {
        ushort4 u = *(const ushort4*)(rr + i * 4);
        s[i * 4 + 0] += bf2f(u.x); s[i * 4 + 1] += bf2f(u.y);
        s[i * 4 + 2] += bf2f(u.z); s[i * 4 + 3] += bf2f(u.w);
      }
    }
    float ic = 1.f / fmaxf((float)dg, 1.f);
    float lm = leafM[g];
#pragma unroll
    for (int i = 0; i < 4; ++i) {
      float4 et = *(const float4*)(endT + c0 + i * 4);
      *(ushort4*)(arow + 256 + c0 + i * 4) = make_ushort4(
          f2bf(s[i * 4 + 0] * ic + lm * et.x), f2bf(s[i * 4 + 1] * ic + lm * et.y),
          f2bf(s[i * 4 + 2] * ic + lm * et.z), f2bf(s[i * 4 + 3] * ic + lm * et.w));
    }
  }
  __syncthreads();
  // layer 1 (K=384): wave w -> cols [w*32, w*32+32)
  f32x4 acc[4][2];
#pragma unroll
  for (int m = 0; m < 4; ++m) {
    acc[m][0] = {0.f, 0.f, 0.f, 0.f}; acc[m][1] = {0.f, 0.f, 0.f, 0.f};
  }
#pragma unroll
  for (int kt = 0; kt < 12; ++kt) {
    short8 a[4];
#pragma unroll
    for (int m = 0; m < 4; ++m)
      a[m] = *(const short8*)(A + (m * 16 + ln) * 392 + kt * 32 + qo);
#pragma unroll
    for (int nn = 0; nn < 2; ++nn) {
      short8 b = *(const short8*)(W1t + (size_t)(w * 32 + nn * 16 + ln) * 384 + kt * 32 + qo);
#pragma unroll
      for (int m = 0; m < 4; ++m) acc[m][nn] = mfma16(a[m], b, acc[m][nn]);
    }
  }
  __syncthreads();  // all A reads done -> overlay O1 into A storage
#pragma unroll
  for (int nn = 0; nn < 2; ++nn) {
    int col = w * 32 + nn * 16 + ln;
    float bb = b1[col];
#pragma unroll
    for (int m = 0; m < 4; ++m)
#pragma unroll
      for (int r = 0; r < 4; ++r)
        A[(m * 16 + quad * 4 + r) * 392 + col] = f2bf(fmaxf(acc[m][nn][r] + bb, 0.f));
  }
  __syncthreads();
  // layer 2 (K=256): wave w -> cols [w*16, w*16+16)
  f32x4 acc2[4];
#pragma unroll
  for (int m = 0; m < 4; ++m) acc2[m] = {0.f, 0.f, 0.f, 0.f};
#pragma unroll
  for (int kt = 0; kt < 8; ++kt) {
    short8 b = *(const short8*)(W2t + (size_t)(w * 16 + ln) * 256 + kt * 32 + qo);
#pragma unroll
    for (int m = 0; m < 4; ++m) {
      short8 a = *(const short8*)(A + (m * 16 + ln) * 392 + kt * 32 + qo);
      acc2[m] = mfma16(a, b, acc2[m]);
    }
  }
  __syncthreads();  // O1 reads done -> overlay fp32 repack (keeps residual in fp32)
  {
    int col = w * 16 + ln;
    float bb = b2[col];
#pragma unroll
    for (int m = 0; m < 4; ++m)
#pragma unroll
      for (int r = 0; r < 4; ++r)
        ((float*)(A + (size_t)(m * 16 + quad * 4 + r) * 392))[col] =
            fmaxf(acc2[m][r] + bb, 0.f);
  }
  __syncthreads();
  if (gr < n) {
    const float* F = (const float*)(A + (size_t)rl * 392);
    float* hrow = hidden + (size_t)gr * DD + c0;
    unsigned short* brow = hbf ? hbf + (size_t)gr * DD + c0 : nullptr;
#pragma unroll
    for (int i = 0; i < 4; ++i) {
      float4 v = *(const float4*)(F + c0 + i * 4);
      float4 h = *(const float4*)(hrow + i * 4);
      h.x += v.x; h.y += v.y; h.z += v.z; h.w += v.w;
      *(float4*)(hrow + i * 4) = h;
      if (brow)
        *(ushort4*)(brow + i * 4) = make_ushort4(f2bf(h.x), f2bf(h.y), f2bf(h.z), f2bf(h.w));
    }
  }
}

extern "C" void kernel_launch(void* const* d_in, const int* in_sizes, int n_in,
                              void* d_out, int out_size, void* d_ws, size_t ws_size,
                              hipStream_t stream) {
  const float* batch  = (const float*)d_in[0];
  const int*   selfI  = (const int*)d_in[1];
  const int*   parI   = (const int*)d_in[2];
  const float* rootM  = (const float*)d_in[3];
  const float* leafM  = (const float*)d_in[4];
  const float* startT = (const float*)d_in[5];
  const float* endT   = (const float*)d_in[6];
  const float* Vw1 = (const float*)d_in[7],  *Vb1 = (const float*)d_in[8];
  const float* Vw2 = (const float*)d_in[9],  *Vb2 = (const float*)d_in[10];
  const float* Ew1 = (const float*)d_in[11], *Eb1 = (const float*)d_in[12];
  const float* Ew2 = (const float*)d_in[13], *Eb2 = (const float*)d_in[14];
  const float* Pw1 = (const float*)d_in[15], *Pb1 = (const float*)d_in[16];
  const float* Pw2 = (const float*)d_in[17], *Pb2 = (const float*)d_in[18];
  const float* Cw1 = (const float*)d_in[19], *Cb1 = (const float*)d_in[20];
  const float* Cw2 = (const float*)d_in[21], *Cb2 = (const float*)d_in[22];
  const float* Aw1 = (const float*)d_in[23], *Ab1 = (const float*)d_in[24];
  const float* Aw2 = (const float*)d_in[25], *Ab2 = (const float*)d_in[26];

  const int N = in_sizes[3];
  const int E = in_sizes[1];
  float* out = (float*)d_out;

  char* p = (char*)d_ws;
  auto nxt = [&](size_t sz) { char* r = p; p += (sz + 255) & ~(size_t)255; return r; };
  unsigned short* SpE = (unsigned short*)nxt((size_t)E * DD * 2);
  unsigned short* ScE = (unsigned short*)nxt((size_t)E * DD * 2);
  int* degP = (int*)nxt((size_t)N * 4);
  int* degC = (int*)nxt((size_t)N * 4);
  int* offP = (int*)nxt((size_t)N * 4);
  int* offC = (int*)nxt((size_t)N * 4);
  int* curP = (int*)nxt((size_t)N * 4);
  int* curC = (int*)nxt((size_t)N * 4);
  int* posP = (int*)nxt((size_t)E * 4);
  int* posC = (int*)nxt((size_t)E * 4);
  int* selfS = (int*)nxt((size_t)E * 4);
  int* parS = (int*)nxt((size_t)E * 4);
  int* posCS = (int*)nxt((size_t)E * 4);
  int* partA = (int*)nxt(4096);
  int* partB = (int*)nxt(4096);
  unsigned short* Vw1t = (unsigned short*)nxt((size_t)128 * 256 * 2);
  unsigned short* Vw2t = (unsigned short*)nxt((size_t)256 * 128 * 2);
  unsigned short* Pw1t = (unsigned short*)nxt((size_t)256 * 256 * 2);
  unsigned short* Pw2t = (unsigned short*)nxt((size_t)256 * 128 * 2);
  unsigned short* Cw1t = (unsigned short*)nxt((size_t)256 * 256 * 2);
  unsigned short* Cw2t = (unsigned short*)nxt((size_t)256 * 128 * 2);
  unsigned short* Aw1t = (unsigned short*)nxt((size_t)384 * 256 * 2);
  unsigned short* Aw2t = (unsigned short*)nxt((size_t)256 * 128 * 2);
  float* b1P = (float*)nxt(256 * 4);
  float* b1C = (float*)nxt(256 * 4);
  // bf16 mirror of hidden (allocated last; optional — runtime ws_size guard)
  unsigned short* Hbf = (unsigned short*)nxt((size_t)N * DD * 2);
  if ((size_t)(p - (char*)d_ws) > ws_size) Hbf = nullptr;

  hipMemsetAsync(degP, 0, (size_t)N * 4, stream);
  hipMemsetAsync(degC, 0, (size_t)N * 4, stream);

  auto blk = [](int total) { return dim3((total + 255) / 256); };
  wconv_all<<<blk(393216), 256, 0, stream>>>(Vw1, Vw2, Pw1, Pw2, Cw1, Cw2, Aw1, Aw2,
                                             Vw1t, Vw2t, Pw1t, Pw2t, Cw1t, Cw2t, Aw1t, Aw2t);

  prep_bias<<<1, 256, 0, stream>>>(Ew1, Eb1, Ew2, Eb2, Pw1, Pb1, Cw1, Cb1, b1P, b1C);
  count_k<<<blk(E), 256, 0, stream>>>(selfI, parI, degP, degC, E);

  int NB = (N + 1023) / 1024;
  scan1_2<<<dim3(NB, 2), 256, 0, stream>>>(degP, offP, partA, degC, offC, partB, N);
  scan2_2<<<2, 256, 0, stream>>>(partA, partB, NB);
  scan3copy<<<blk(N), 256, 0, stream>>>(offP, partA, curP, offC, partB, curC, N);
  pos_k<<<blk(E), 256, 0, stream>>>(selfI, parI, curP, curC, posP, posC, E);
  reorder_k<<<blk(E), 256, 0, stream>>>(selfI, parI, posP, posC, selfS, parS, posCS, E);

  dim3 gN((N + 63) / 64), gE((E + 63) / 64);
  v_kernel<<<gN, 512, 0, stream>>>(batch, Vw1t, Vw2t, Vb1, Vb2, out, Hbf, N);

  for (int hop = 0; hop < 3; ++hop) {
    edge_kernel<<<gE, 512, 0, stream>>>(out, Hbf, selfS, parS, posCS,
                                        Pw1t, Pw2t, Cw1t, Cw2t, b1P, b1C, Pb2, Cb2,
                                        SpE, ScE, E);
    node_kernel<<<gN, 512, 0, stream>>>(out, Hbf, SpE, ScE, offP, degP, offC, degC,
                                        rootM, leafM, startT, endT,
                                        Aw1t, Aw2t, Ab1, Ab2, N);
  }
}